// Round 1
// baseline (5870.796 us; speedup 1.0000x reference)
//
#include <hip/hip_runtime.h>
#include <math.h>

#define NB 16
#define NHW 3136
#define NROWS 50176          // 16*56*56
#define CD 384
#define CH2 192
#define SCL 0.20412414523193154f   // 24^-0.5

static __device__ __forceinline__ float gelu_exact(float v) {
  return 0.5f * v * (1.0f + erff(v * 0.70710678118654752440f));
}

// ---------------- LayerNorm (one wave per row) ----------------
template<int CN>
__global__ __launch_bounds__(256) void ln_k(const float* __restrict__ x,
    const float* __restrict__ w, const float* __restrict__ b,
    float* __restrict__ out)
{
  constexpr int NPER = CN / 64;
  int wave = threadIdx.x >> 6, lane = threadIdx.x & 63;
  int row = blockIdx.x * 4 + wave;
  const float* xp = x + (size_t)row * CN;
  float v[NPER];
  float s = 0.f;
  #pragma unroll
  for (int i = 0; i < NPER; i++) { v[i] = xp[lane + 64*i]; s += v[i]; }
  #pragma unroll
  for (int off = 32; off; off >>= 1) s += __shfl_xor(s, off);
  float mean = s * (1.0f / CN);
  float vs = 0.f;
  #pragma unroll
  for (int i = 0; i < NPER; i++) { float d = v[i] - mean; vs += d*d; }
  #pragma unroll
  for (int off = 32; off; off >>= 1) vs += __shfl_xor(vs, off);
  float rstd = rsqrtf(vs * (1.0f / CN) + 1e-6f);
  float* op = out + (size_t)row * CN;
  #pragma unroll
  for (int i = 0; i < NPER; i++) {
    int c = lane + 64*i;
    op[c] = (v[i] - mean) * rstd * w[c] + b[c];
  }
}

// ---------------- 8x8 average pool of concat(xn, xen) ----------------
// grid: 16*49 blocks, 576 threads. pooled[b][py][px][c] row-major [784,576]
__global__ void pool_k(const float* __restrict__ xn, const float* __restrict__ xen,
                       float* __restrict__ pooled)
{
  int c = threadIdx.x;           // 0..575
  int blk = blockIdx.x;          // 0..783
  int b = blk / 49, q = blk % 49;
  int py = q / 7, px = q % 7;
  float s = 0.f;
  if (c < CD) {
    const float* base = xn + (((size_t)(b*56 + py*8))*56 + px*8) * CD + c;
    #pragma unroll
    for (int iy = 0; iy < 8; iy++)
      for (int ix = 0; ix < 8; ix++)
        s += base[(iy*56 + ix) * CD];
  } else {
    int cc = c - CD;
    const float* base = xen + (((size_t)(b*56 + py*8))*56 + px*8) * CH2 + cc;
    #pragma unroll
    for (int iy = 0; iy < 8; iy++)
      for (int ix = 0; ix < 8; ix++)
        s += base[(iy*56 + ix) * CH2];
  }
  pooled[(size_t)blk * 576 + c] = s * (1.0f / 64.0f);
}

// ---------------- fp32 tiled GEMM: C[M,N] = A[M,K] @ B[K,N] (+bias) ----------------
// MODE 0: store, MODE 1: gelu(store), MODE 2: C *= value
template<int MODE>
__global__ __launch_bounds__(256) void gemm_k(
    const float* __restrict__ A, int lda,
    const float* __restrict__ B, int ldb,
    const float* __restrict__ bias,
    float* __restrict__ C, int ldc,
    int M, int N, int K)
{
  __shared__ float As[16][128 + 4];
  __shared__ float Bs[16][64 + 4];
  const int tid = threadIdx.x;
  const int tx = tid & 15;        // col group
  const int ty = tid >> 4;        // row group
  const int mbase = blockIdx.y * 128;
  const int nbase = blockIdx.x * 64;
  float acc[8][4] = {};
  for (int k0 = 0; k0 < K; k0 += 16) {
    #pragma unroll
    for (int r = 0; r < 2; r++) {
      int idx = tid + r * 256;        // 0..511
      int m = idx >> 2;               // 0..127
      int kq = (idx & 3) * 4;         // 0,4,8,12
      float4 av = {0.f, 0.f, 0.f, 0.f};
      if (mbase + m < M)
        av = *reinterpret_cast<const float4*>(&A[(size_t)(mbase + m) * lda + k0 + kq]);
      As[kq + 0][m] = av.x; As[kq + 1][m] = av.y;
      As[kq + 2][m] = av.z; As[kq + 3][m] = av.w;
    }
    {
      int k = tid >> 4;               // 0..15
      int nq = (tid & 15) * 4;
      float4 bv = *reinterpret_cast<const float4*>(&B[(size_t)(k0 + k) * ldb + nbase + nq]);
      *reinterpret_cast<float4*>(&Bs[k][nq]) = bv;
    }
    __syncthreads();
    #pragma unroll
    for (int k = 0; k < 16; k++) {
      float a0[8], b0[4];
      #pragma unroll
      for (int i = 0; i < 8; i++) a0[i] = As[k][ty*8 + i];
      #pragma unroll
      for (int j = 0; j < 4; j++) b0[j] = Bs[k][tx*4 + j];
      #pragma unroll
      for (int i = 0; i < 8; i++)
        #pragma unroll
        for (int j = 0; j < 4; j++)
          acc[i][j] += a0[i] * b0[j];
    }
    __syncthreads();
  }
  float bv[4];
  #pragma unroll
  for (int j = 0; j < 4; j++) bv[j] = bias[nbase + tx*4 + j];
  #pragma unroll
  for (int i = 0; i < 8; i++) {
    int m = mbase + ty*8 + i;
    if (m < M) {
      float* cp = &C[(size_t)m * ldc + nbase + tx*4];
      #pragma unroll
      for (int j = 0; j < 4; j++) {
        float v = acc[i][j] + bv[j];
        if (MODE == 1) v = gelu_exact(v);
        if (MODE == 2) v = cp[j] * v;
        cp[j] = v;
      }
    }
  }
}

// ---------------- depthwise 7x7 conv, pad 3, NHWC ----------------
template<int CH>
__global__ __launch_bounds__(256) void dwconv_k(const float* __restrict__ in,
    const float* __restrict__ wgt, const float* __restrict__ bias,
    float* __restrict__ out)
{
  int idx = blockIdx.x * 256 + threadIdx.x;
  if (idx >= NB * NHW * CH) return;
  int c = idx % CH;
  int pos = idx / CH;
  int x = pos % 56, y = (pos / 56) % 56, b = pos / NHW;
  float s = bias[c];
  const float* wp = wgt + c * 49;
  #pragma unroll
  for (int dy = 0; dy < 7; dy++) {
    int yy = y + dy - 3;
    if ((unsigned)yy < 56u) {
      const float* ip = in + ((size_t)(b*56 + yy) * 56) * CH + c;
      #pragma unroll
      for (int dx = 0; dx < 7; dx++) {
        int xx = x + dx - 3;
        if ((unsigned)xx < 56u) s += ip[xx * CH] * wp[dy*7 + dx];
      }
    }
  }
  out[idx] = s;
}

// ---------------- attention: 49 queries vs 3136 keys, per (b,head) ----------------
// grid 128 blocks (b*8+h), 256 threads. lane = query (49 active), wave splits keys.
// mbuf [784,192]; kv [B,HW,2,8,24] flattened stride 384; obuf [B,192,49]
__global__ __launch_bounds__(256) void attn_k(const float* __restrict__ mbuf,
    const float* __restrict__ kv, float* __restrict__ obuf)
{
  __shared__ float red[4][64][26];
  int bh = blockIdx.x;
  int b = bh >> 3, h = bh & 7;
  int wave = threadIdx.x >> 6, lane = threadIdx.x & 63;
  int qq = lane < 49 ? lane : 48;
  float mq[24];
  const float* mp = mbuf + ((size_t)(b*49 + qq)) * 192 + h * 24;
  #pragma unroll
  for (int d = 0; d < 24; d++) mq[d] = mp[d] * SCL;
  float mx = -1e30f, sm = 0.f, acc[24] = {};
  int k0 = wave * 784, k1 = k0 + 784;
  for (int key = k0; key < k1; key++) {
    const float* kp = kv + ((size_t)(b*NHW + key)) * 384 + h * 24;
    float s = 0.f;
    #pragma unroll
    for (int d = 0; d < 24; d++) s += mq[d] * kp[d];
    float nm = fmaxf(mx, s);
    float f = __expf(mx - nm);
    float p = __expf(s - nm);
    sm = sm * f + p;
    const float* vp = kp + 192;
    #pragma unroll
    for (int d = 0; d < 24; d++) acc[d] = acc[d] * f + p * vp[d];
    mx = nm;
  }
  red[wave][lane][0] = mx;
  red[wave][lane][1] = sm;
  #pragma unroll
  for (int d = 0; d < 24; d++) red[wave][lane][2 + d] = acc[d];
  __syncthreads();
  if (wave == 0 && lane < 49) {
    float gm = -1e30f, gs = 0.f, ga[24] = {};
    #pragma unroll
    for (int w = 0; w < 4; w++) {
      float wm = red[w][lane][0], wsm = red[w][lane][1];
      float nm = fmaxf(gm, wm);
      float f1 = __expf(gm - nm), f2 = __expf(wm - nm);
      gs = gs * f1 + wsm * f2;
      #pragma unroll
      for (int d = 0; d < 24; d++)
        ga[d] = ga[d] * f1 + red[w][lane][2 + d] * f2;
      gm = nm;
    }
    float inv = 1.0f / gs;
    float* op = obuf + ((size_t)b * 192 + h * 24) * 49 + lane;
    #pragma unroll
    for (int d = 0; d < 24; d++) op[d * 49] = ga[d] * inv;
  }
}

// ---------------- bilinear 7x7 -> 56x56 upsample into cat[:,384:576] ----------------
__global__ __launch_bounds__(256) void upsample_k(const float* __restrict__ obuf,
    float* __restrict__ cat)
{
  int idx = blockIdx.x * 256 + threadIdx.x;
  if (idx >= NB * NHW * CH2) return;
  int c = idx % CH2;
  int pos = idx / CH2;
  int x = pos % 56, y = (pos / 56) % 56, b = pos / NHW;
  float sy = (y + 0.5f) * 0.125f - 0.5f;
  float sx = (x + 0.5f) * 0.125f - 0.5f;
  int y0 = (int)floorf(sy); float ty = sy - (float)y0;
  int x0 = (int)floorf(sx); float tx = sx - (float)x0;
  int y0c = max(y0, 0), y1c = min(y0 + 1, 6);
  int x0c = max(x0, 0), x1c = min(x0 + 1, 6);
  const float* ob = obuf + ((size_t)b * 192 + c) * 49;
  float v = (1.f - ty) * ((1.f - tx) * ob[y0c*7 + x0c] + tx * ob[y0c*7 + x1c])
          +        ty  * ((1.f - tx) * ob[y1c*7 + x0c] + tx * ob[y1c*7 + x1c]);
  cat[(size_t)pos * 768 + 384 + c] = v;
}

extern "C" void kernel_launch(void* const* d_in, const int* in_sizes, int n_in,
                              void* d_out, int out_size, void* d_ws, size_t ws_size,
                              hipStream_t stream) {
  const float* x       = (const float*)d_in[0];
  const float* x_e     = (const float*)d_in[1];
  const float* norm_w  = (const float*)d_in[2];
  const float* norm_b  = (const float*)d_in[3];
  const float* norme_w = (const float*)d_in[4];
  const float* norme_b = (const float*)d_in[5];
  const float* q_w     = (const float*)d_in[6];
  const float* q_b     = (const float*)d_in[7];
  const float* qcut_w  = (const float*)d_in[8];
  const float* qcut_b  = (const float*)d_in[9];
  const float* a_w     = (const float*)d_in[10];
  const float* a_b     = (const float*)d_in[11];
  const float* l_w     = (const float*)d_in[12];
  const float* l_b     = (const float*)d_in[13];
  const float* conv_w  = (const float*)d_in[14];
  const float* conv_b  = (const float*)d_in[15];
  const float* econv_w = (const float*)d_in[16];
  const float* econv_b = (const float*)d_in[17];
  const float* efore_w = (const float*)d_in[18];
  const float* efore_b = (const float*)d_in[19];
  const float* eback_w = (const float*)d_in[20];
  const float* eback_b = (const float*)d_in[21];
  const float* kv_w    = (const float*)d_in[22];
  const float* kv_b    = (const float*)d_in[23];
  const float* scl_w   = (const float*)d_in[24];
  const float* scl_b   = (const float*)d_in[25];
  const float* proj_w  = (const float*)d_in[26];
  const float* proj_b  = (const float*)d_in[27];
  const float* proje_w = (const float*)d_in[28];
  const float* proje_b = (const float*)d_in[29];
  float* out = (float*)d_out;

  float* ws = (float*)d_ws;
  float* xn     = ws;                       // 19267584
  float* xen    = xn  + 19267584;           //  9633792
  float* lx     = xen + 9633792;            // 19267584
  float* kvbuf  = lx  + 19267584;           // 19267584
  float* cat    = kvbuf + 19267584;         // 38535168
  float* pooled = cat + 38535168;           //   451584
  float* mbuf   = pooled + 451584;          //   150528
  float* obuf   = mbuf + 150528;            //   150528
  float* convbuf  = xn;                     // reuse after xn consumed
  float* efbuf    = lx;                     // reuse after kv gemm
  float* econvbuf = kvbuf;                  // reuse after attention

  // 1-2: LayerNorms
  ln_k<384><<<NROWS/4, 256, 0, stream>>>(x,   norm_w,  norm_b,  xn);
  ln_k<192><<<NROWS/4, 256, 0, stream>>>(x_e, norme_w, norme_b, xen);
  // 3: pool, 4: m = pooled @ scl_w
  pool_k<<<NB*49, 576, 0, stream>>>(xn, xen, pooled);
  gemm_k<0><<<dim3(3, 7), 256, 0, stream>>>(pooled, 576, scl_w, 192, scl_b,
                                            mbuf, 192, 784, 192, 576);
  // 5: q -> cat[:, :384]
  gemm_k<0><<<dim3(6, 392), 256, 0, stream>>>(xn, 384, q_w, 384, q_b,
                                              cat, 768, NROWS, 384, 384);
  // 6: cut -> cat[:, 576:768]
  gemm_k<0><<<dim3(3, 392), 256, 0, stream>>>(xn, 384, qcut_w, 192, qcut_b,
                                              cat + 576, 768, NROWS, 192, 384);
  // 7: lx = gelu(xn @ l_w + l_b)
  gemm_k<1><<<dim3(6, 392), 256, 0, stream>>>(xn, 384, l_w, 384, l_b,
                                              lx, 384, NROWS, 384, 384);
  // 8: dwconv(lx) -> convbuf ; 9: cat_g *= (convbuf @ a_w + a_b)
  dwconv_k<384><<<(NB*NHW*384)/256, 256, 0, stream>>>(lx, conv_w, conv_b, convbuf);
  gemm_k<2><<<dim3(6, 392), 256, 0, stream>>>(convbuf, 384, a_w, 384, a_b,
                                              cat, 768, NROWS, 384, 384);
  // 10: kv = lx @ kv_w + kv_b
  gemm_k<0><<<dim3(6, 392), 256, 0, stream>>>(lx, 384, kv_w, 384, kv_b,
                                              kvbuf, 384, NROWS, 384, 384);
  // 11: attention -> obuf ; 12: upsample -> cat[:,384:576]
  attn_k<<<NB*8, 256, 0, stream>>>(mbuf, kvbuf, obuf);
  upsample_k<<<(NB*NHW*CH2)/256, 256, 0, stream>>>(obuf, cat);
  // 13: ef = xen @ efore_w ; 14: dwconv ; 15: cat_cut *= (econv @ eback_w + eback_b)
  gemm_k<0><<<dim3(3, 392), 256, 0, stream>>>(xen, 192, efore_w, 192, efore_b,
                                              efbuf, 192, NROWS, 192, 192);
  dwconv_k<192><<<(NB*NHW*192)/256, 256, 0, stream>>>(efbuf, econv_w, econv_b, econvbuf);
  gemm_k<2><<<dim3(3, 392), 256, 0, stream>>>(econvbuf, 192, eback_w, 192, eback_b,
                                              cat + 576, 768, NROWS, 192, 192);
  // 16-17: projections
  gemm_k<0><<<dim3(6, 392), 256, 0, stream>>>(cat, 768, proj_w, 384, proj_b,
                                              out, 384, NROWS, 384, 768);
  gemm_k<0><<<dim3(3, 392), 256, 0, stream>>>(cat, 768, proje_w, 192, proje_b,
                                              out + 19267584, 192, NROWS, 192, 768);
}

// Round 2
// 2609.725 us; speedup vs baseline: 2.2496x; 2.2496x over previous
//
#include <hip/hip_runtime.h>
#include <math.h>

#define NB 16
#define NHW 3136
#define NROWS 50176          // 16*56*56
#define CD 384
#define CH2 192
#define SCL 0.20412414523193154f   // 24^-0.5

static __device__ __forceinline__ float gelu_exact(float v) {
  return 0.5f * v * (1.0f + erff(v * 0.70710678118654752440f));
}

// ---------------- LayerNorm (one wave per row) ----------------
template<int CN>
__global__ __launch_bounds__(256) void ln_k(const float* __restrict__ x,
    const float* __restrict__ w, const float* __restrict__ b,
    float* __restrict__ out)
{
  constexpr int NPER = CN / 64;
  int wave = threadIdx.x >> 6, lane = threadIdx.x & 63;
  int row = blockIdx.x * 4 + wave;
  const float* xp = x + (size_t)row * CN;
  float v[NPER];
  float s = 0.f;
  #pragma unroll
  for (int i = 0; i < NPER; i++) { v[i] = xp[lane + 64*i]; s += v[i]; }
  #pragma unroll
  for (int off = 32; off; off >>= 1) s += __shfl_xor(s, off);
  float mean = s * (1.0f / CN);
  float vs = 0.f;
  #pragma unroll
  for (int i = 0; i < NPER; i++) { float d = v[i] - mean; vs += d*d; }
  #pragma unroll
  for (int off = 32; off; off >>= 1) vs += __shfl_xor(vs, off);
  float rstd = rsqrtf(vs * (1.0f / CN) + 1e-6f);
  float* op = out + (size_t)row * CN;
  #pragma unroll
  for (int i = 0; i < NPER; i++) {
    int c = lane + 64*i;
    op[c] = (v[i] - mean) * rstd * w[c] + b[c];
  }
}

// ---------------- 8x8 average pool of concat(xn, xen) ----------------
__global__ void pool_k(const float* __restrict__ xn, const float* __restrict__ xen,
                       float* __restrict__ pooled)
{
  int c = threadIdx.x;           // 0..575
  int blk = blockIdx.x;          // 0..783
  int b = blk / 49, q = blk % 49;
  int py = q / 7, px = q % 7;
  float s = 0.f;
  if (c < CD) {
    const float* base = xn + (((size_t)(b*56 + py*8))*56 + px*8) * CD + c;
    #pragma unroll
    for (int iy = 0; iy < 8; iy++)
      for (int ix = 0; ix < 8; ix++)
        s += base[(iy*56 + ix) * CD];
  } else {
    int cc = c - CD;
    const float* base = xen + (((size_t)(b*56 + py*8))*56 + px*8) * CH2 + cc;
    #pragma unroll
    for (int iy = 0; iy < 8; iy++)
      for (int ix = 0; ix < 8; ix++)
        s += base[(iy*56 + ix) * CH2];
  }
  pooled[(size_t)blk * 576 + c] = s * (1.0f / 64.0f);
}

// ---------------- fp32 tiled GEMM: C[M,N] = A[M,K] @ B[K,N] (+bias) ----------------
template<int MODE>
__global__ __launch_bounds__(256) void gemm_k(
    const float* __restrict__ A, int lda,
    const float* __restrict__ B, int ldb,
    const float* __restrict__ bias,
    float* __restrict__ C, int ldc,
    int M, int N, int K)
{
  __shared__ float As[16][128 + 4];
  __shared__ float Bs[16][64 + 4];
  const int tid = threadIdx.x;
  const int tx = tid & 15;        // col group
  const int ty = tid >> 4;        // row group
  const int mbase = blockIdx.y * 128;
  const int nbase = blockIdx.x * 64;
  float acc[8][4] = {};
  for (int k0 = 0; k0 < K; k0 += 16) {
    #pragma unroll
    for (int r = 0; r < 2; r++) {
      int idx = tid + r * 256;        // 0..511
      int m = idx >> 2;               // 0..127
      int kq = (idx & 3) * 4;         // 0,4,8,12
      float4 av = {0.f, 0.f, 0.f, 0.f};
      if (mbase + m < M)
        av = *reinterpret_cast<const float4*>(&A[(size_t)(mbase + m) * lda + k0 + kq]);
      As[kq + 0][m] = av.x; As[kq + 1][m] = av.y;
      As[kq + 2][m] = av.z; As[kq + 3][m] = av.w;
    }
    {
      int k = tid >> 4;               // 0..15
      int nq = (tid & 15) * 4;
      float4 bv = *reinterpret_cast<const float4*>(&B[(size_t)(k0 + k) * ldb + nbase + nq]);
      *reinterpret_cast<float4*>(&Bs[k][nq]) = bv;
    }
    __syncthreads();
    #pragma unroll
    for (int k = 0; k < 16; k++) {
      float a0[8], b0[4];
      #pragma unroll
      for (int i = 0; i < 8; i++) a0[i] = As[k][ty*8 + i];
      #pragma unroll
      for (int j = 0; j < 4; j++) b0[j] = Bs[k][tx*4 + j];
      #pragma unroll
      for (int i = 0; i < 8; i++)
        #pragma unroll
        for (int j = 0; j < 4; j++)
          acc[i][j] += a0[i] * b0[j];
    }
    __syncthreads();
  }
  float bv[4];
  #pragma unroll
  for (int j = 0; j < 4; j++) bv[j] = bias[nbase + tx*4 + j];
  #pragma unroll
  for (int i = 0; i < 8; i++) {
    int m = mbase + ty*8 + i;
    if (m < M) {
      float* cp = &C[(size_t)m * ldc + nbase + tx*4];
      #pragma unroll
      for (int j = 0; j < 4; j++) {
        float v = acc[i][j] + bv[j];
        if (MODE == 1) v = gelu_exact(v);
        if (MODE == 2) v = cp[j] * v;
        cp[j] = v;
      }
    }
  }
}

// ---------------- depthwise 7x7 conv, pad 3, NHWC — LDS-tiled ----------------
// grid: (49 tiles, CH/64 chunks, 16 batch), 256 threads.
// Block computes an 8x8 output tile x 64 channels. Stages 14x14x64 input halo
// + 64x49 weights into LDS (all coalesced), then sliding-window compute.
template<int CH>
__global__ __launch_bounds__(256) void dwconv_k(const float* __restrict__ in,
    const float* __restrict__ wgt, const float* __restrict__ bias,
    float* __restrict__ out)
{
  __shared__ float in_t[196 * 64];   // [pos=iy*14+ix][c]  50176 B
  __shared__ float wlds[64 * 49];    // [c*49+tap]         12544 B

  const int t = threadIdx.x;
  const int c = t & 63;
  const int pg = t >> 6;             // wave id 0..3
  const int tile = blockIdx.x;       // 0..48
  const int cbase = blockIdx.y * 64;
  const int b = blockIdx.z;
  const int oy0 = (tile / 7) * 8;
  const int ox0 = (tile % 7) * 8;

  // stage input halo: each wave handles positions p = pg + 4*i (49 iters)
  #pragma unroll 7
  for (int i = 0; i < 49; i++) {
    int p = pg + 4 * i;              // 0..195
    int iy = p / 14, ix = p % 14;
    int gy = oy0 + iy - 3;
    int gx = ox0 + ix - 3;
    float v = 0.f;
    if ((unsigned)gy < 56u && (unsigned)gx < 56u)
      v = in[((size_t)(b * 56 + gy) * 56 + gx) * CH + cbase + c];
    in_t[p * 64 + c] = v;
  }
  // stage weights: 3136 contiguous floats starting at cbase*49
  #pragma unroll
  for (int i = 0; i < 13; i++) {
    int j = t + 256 * i;
    if (j < 64 * 49) wlds[j] = wgt[(size_t)cbase * 49 + j];
  }
  __syncthreads();

  float bv = bias[cbase + c];
  float acc[2][8];
  #pragma unroll
  for (int r = 0; r < 2; r++)
    #pragma unroll
    for (int x = 0; x < 8; x++) acc[r][x] = bv;

  #pragma unroll
  for (int dy = 0; dy < 7; dy++) {
    float wrow[7];
    #pragma unroll
    for (int dx = 0; dx < 7; dx++) wrow[dx] = wlds[c * 49 + dy * 7 + dx];
    #pragma unroll
    for (int r = 0; r < 2; r++) {
      int oy = pg * 2 + r;           // 0..7
      int iy = oy + dy;              // 0..13
      float win[14];
      #pragma unroll
      for (int j = 0; j < 14; j++) win[j] = in_t[(iy * 14 + j) * 64 + c];
      #pragma unroll
      for (int dx = 0; dx < 7; dx++)
        #pragma unroll
        for (int x = 0; x < 8; x++)
          acc[r][x] += win[x + dx] * wrow[dx];
    }
  }

  #pragma unroll
  for (int r = 0; r < 2; r++) {
    int oy = pg * 2 + r;
    #pragma unroll
    for (int x = 0; x < 8; x++) {
      out[((size_t)(b * 56 + oy0 + oy) * 56 + ox0 + x) * CH + cbase + c] = acc[r][x];
    }
  }
}

// ---------------- attention: 49 queries vs 3136 keys, per (b,head) ----------------
__global__ __launch_bounds__(256) void attn_k(const float* __restrict__ mbuf,
    const float* __restrict__ kv, float* __restrict__ obuf)
{
  __shared__ float red[4][64][26];
  int bh = blockIdx.x;
  int b = bh >> 3, h = bh & 7;
  int wave = threadIdx.x >> 6, lane = threadIdx.x & 63;
  int qq = lane < 49 ? lane : 48;
  float mq[24];
  const float* mp = mbuf + ((size_t)(b*49 + qq)) * 192 + h * 24;
  #pragma unroll
  for (int d = 0; d < 24; d++) mq[d] = mp[d] * SCL;
  float mx = -1e30f, sm = 0.f, acc[24] = {};
  int k0 = wave * 784, k1 = k0 + 784;
  for (int key = k0; key < k1; key++) {
    const float* kp = kv + ((size_t)(b*NHW + key)) * 384 + h * 24;
    float s = 0.f;
    #pragma unroll
    for (int d = 0; d < 24; d++) s += mq[d] * kp[d];
    float nm = fmaxf(mx, s);
    float f = __expf(mx - nm);
    float p = __expf(s - nm);
    sm = sm * f + p;
    const float* vp = kp + 192;
    #pragma unroll
    for (int d = 0; d < 24; d++) acc[d] = acc[d] * f + p * vp[d];
    mx = nm;
  }
  red[wave][lane][0] = mx;
  red[wave][lane][1] = sm;
  #pragma unroll
  for (int d = 0; d < 24; d++) red[wave][lane][2 + d] = acc[d];
  __syncthreads();
  if (wave == 0 && lane < 49) {
    float gm = -1e30f, gs = 0.f, ga[24] = {};
    #pragma unroll
    for (int w = 0; w < 4; w++) {
      float wm = red[w][lane][0], wsm = red[w][lane][1];
      float nm = fmaxf(gm, wm);
      float f1 = __expf(gm - nm), f2 = __expf(wm - nm);
      gs = gs * f1 + wsm * f2;
      #pragma unroll
      for (int d = 0; d < 24; d++)
        ga[d] = ga[d] * f1 + red[w][lane][2 + d] * f2;
      gm = nm;
    }
    float inv = 1.0f / gs;
    float* op = obuf + ((size_t)b * 192 + h * 24) * 49 + lane;
    #pragma unroll
    for (int d = 0; d < 24; d++) op[d * 49] = ga[d] * inv;
  }
}

// ---------------- bilinear 7x7 -> 56x56 upsample into cat[:,384:576] ----------------
__global__ __launch_bounds__(256) void upsample_k(const float* __restrict__ obuf,
    float* __restrict__ cat)
{
  int idx = blockIdx.x * 256 + threadIdx.x;
  if (idx >= NB * NHW * CH2) return;
  int c = idx % CH2;
  int pos = idx / CH2;
  int x = pos % 56, y = (pos / 56) % 56, b = pos / NHW;
  float sy = (y + 0.5f) * 0.125f - 0.5f;
  float sx = (x + 0.5f) * 0.125f - 0.5f;
  int y0 = (int)floorf(sy); float ty = sy - (float)y0;
  int x0 = (int)floorf(sx); float tx = sx - (float)x0;
  int y0c = max(y0, 0), y1c = min(y0 + 1, 6);
  int x0c = max(x0, 0), x1c = min(x0 + 1, 6);
  const float* ob = obuf + ((size_t)b * 192 + c) * 49;
  float v = (1.f - ty) * ((1.f - tx) * ob[y0c*7 + x0c] + tx * ob[y0c*7 + x1c])
          +        ty  * ((1.f - tx) * ob[y1c*7 + x0c] + tx * ob[y1c*7 + x1c]);
  cat[(size_t)pos * 768 + 384 + c] = v;
}

extern "C" void kernel_launch(void* const* d_in, const int* in_sizes, int n_in,
                              void* d_out, int out_size, void* d_ws, size_t ws_size,
                              hipStream_t stream) {
  const float* x       = (const float*)d_in[0];
  const float* x_e     = (const float*)d_in[1];
  const float* norm_w  = (const float*)d_in[2];
  const float* norm_b  = (const float*)d_in[3];
  const float* norme_w = (const float*)d_in[4];
  const float* norme_b = (const float*)d_in[5];
  const float* q_w     = (const float*)d_in[6];
  const float* q_b     = (const float*)d_in[7];
  const float* qcut_w  = (const float*)d_in[8];
  const float* qcut_b  = (const float*)d_in[9];
  const float* a_w     = (const float*)d_in[10];
  const float* a_b     = (const float*)d_in[11];
  const float* l_w     = (const float*)d_in[12];
  const float* l_b     = (const float*)d_in[13];
  const float* conv_w  = (const float*)d_in[14];
  const float* conv_b  = (const float*)d_in[15];
  const float* econv_w = (const float*)d_in[16];
  const float* econv_b = (const float*)d_in[17];
  const float* efore_w = (const float*)d_in[18];
  const float* efore_b = (const float*)d_in[19];
  const float* eback_w = (const float*)d_in[20];
  const float* eback_b = (const float*)d_in[21];
  const float* kv_w    = (const float*)d_in[22];
  const float* kv_b    = (const float*)d_in[23];
  const float* scl_w   = (const float*)d_in[24];
  const float* scl_b   = (const float*)d_in[25];
  const float* proj_w  = (const float*)d_in[26];
  const float* proj_b  = (const float*)d_in[27];
  const float* proje_w = (const float*)d_in[28];
  const float* proje_b = (const float*)d_in[29];
  float* out = (float*)d_out;

  float* ws = (float*)d_ws;
  float* xn     = ws;                       // 19267584
  float* xen    = xn  + 19267584;           //  9633792
  float* lx     = xen + 9633792;            // 19267584
  float* kvbuf  = lx  + 19267584;           // 19267584
  float* cat    = kvbuf + 19267584;         // 38535168
  float* pooled = cat + 38535168;           //   451584
  float* mbuf   = pooled + 451584;          //   150528
  float* obuf   = mbuf + 150528;            //   150528
  float* convbuf  = xn;                     // reuse after xn consumed
  float* efbuf    = lx;                     // reuse after kv gemm
  float* econvbuf = kvbuf;                  // reuse after attention

  // 1-2: LayerNorms
  ln_k<384><<<NROWS/4, 256, 0, stream>>>(x,   norm_w,  norm_b,  xn);
  ln_k<192><<<NROWS/4, 256, 0, stream>>>(x_e, norme_w, norme_b, xen);
  // 3: pool, 4: m = pooled @ scl_w
  pool_k<<<NB*49, 576, 0, stream>>>(xn, xen, pooled);
  gemm_k<0><<<dim3(3, 7), 256, 0, stream>>>(pooled, 576, scl_w, 192, scl_b,
                                            mbuf, 192, 784, 192, 576);
  // 5: q -> cat[:, :384]
  gemm_k<0><<<dim3(6, 392), 256, 0, stream>>>(xn, 384, q_w, 384, q_b,
                                              cat, 768, NROWS, 384, 384);
  // 6: cut -> cat[:, 576:768]
  gemm_k<0><<<dim3(3, 392), 256, 0, stream>>>(xn, 384, qcut_w, 192, qcut_b,
                                              cat + 576, 768, NROWS, 192, 384);
  // 7: lx = gelu(xn @ l_w + l_b)
  gemm_k<1><<<dim3(6, 392), 256, 0, stream>>>(xn, 384, l_w, 384, l_b,
                                              lx, 384, NROWS, 384, 384);
  // 8: dwconv(lx) -> convbuf ; 9: cat_g *= (convbuf @ a_w + a_b)
  dwconv_k<384><<<dim3(49, 6, NB), 256, 0, stream>>>(lx, conv_w, conv_b, convbuf);
  gemm_k<2><<<dim3(6, 392), 256, 0, stream>>>(convbuf, 384, a_w, 384, a_b,
                                              cat, 768, NROWS, 384, 384);
  // 10: kv = lx @ kv_w + kv_b
  gemm_k<0><<<dim3(6, 392), 256, 0, stream>>>(lx, 384, kv_w, 384, kv_b,
                                              kvbuf, 384, NROWS, 384, 384);
  // 11: attention -> obuf ; 12: upsample -> cat[:,384:576]
  attn_k<<<NB*8, 256, 0, stream>>>(mbuf, kvbuf, obuf);
  upsample_k<<<(NB*NHW*CH2)/256, 256, 0, stream>>>(obuf, cat);
  // 13: ef = xen @ efore_w ; 14: dwconv ; 15: cat_cut *= (econv @ eback_w + eback_b)
  gemm_k<0><<<dim3(3, 392), 256, 0, stream>>>(xen, 192, efore_w, 192, efore_b,
                                              efbuf, 192, NROWS, 192, 192);
  dwconv_k<192><<<dim3(49, 3, NB), 256, 0, stream>>>(efbuf, econv_w, econv_b, econvbuf);
  gemm_k<2><<<dim3(3, 392), 256, 0, stream>>>(econvbuf, 192, eback_w, 192, eback_b,
                                              cat + 576, 768, NROWS, 192, 192);
  // 16-17: projections
  gemm_k<0><<<dim3(6, 392), 256, 0, stream>>>(cat, 768, proj_w, 384, proj_b,
                                              out, 384, NROWS, 384, 768);
  gemm_k<0><<<dim3(3, 392), 256, 0, stream>>>(cat, 768, proje_w, 192, proje_b,
                                              out + 19267584, 192, NROWS, 192, 768);
}